// Round 2
// baseline (232.200 us; speedup 1.0000x reference)
//
#include <hip/hip_runtime.h>
#include <math.h>

// Problem constants: token shape (b=16, c=16, n=25, h=16, w=128)
#define SB 819200   // batch stride = c*n*h*w
#define SC 51200    // c stride    = n*h*w
#define SN 2048     // n stride    = h*w
#define CH 256      // c*h  (t dim)
#define NW 3200     // n*w  (k dim of gemm1, s dim of gemm2)
#define NPARTS 10
#define PARTLEN 320         // 3200 / 10
#define BK 32               // k-chunk per stage
#define NCH 10              // PARTLEN / BK
#define SPART 1048576       // 16*256*256 floats per split-K partial
#define G1BLOCKS 480        // 3 tiles * 10 parts * 16 b

typedef __bf16 bf16x8 __attribute__((ext_vector_type(8)));
typedef __bf16 bf16x4 __attribute__((ext_vector_type(4)));
typedef __bf16 bf16x2 __attribute__((ext_vector_type(2)));
typedef float  f32x4  __attribute__((ext_vector_type(4)));

__device__ __forceinline__ bf16x8 cvt8(float4 a, float4 b) {
    bf16x8 r;
    r[0] = (__bf16)a.x; r[1] = (__bf16)a.y; r[2] = (__bf16)a.z; r[3] = (__bf16)a.w;
    r[4] = (__bf16)b.x; r[5] = (__bf16)b.y; r[6] = (__bf16)b.z; r[7] = (__bf16)b.w;
    return r;
}

__device__ __forceinline__ float dot4(float4 a) {
    return a.x * a.x + a.y * a.y + a.z * a.z + a.w * a.w;
}

// ---------------------------------------------------------------------------
// Kernel 1: split-K bf16-MFMA score GEMM + fused row sum-of-squares.
// Spart[p][b][t][r] = sum_{k in part p} Q[t][k]*K[r][k], fp32.
// 128x128 tile, 4 waves of 64x64, causal 3-tile, 480 blocks (2/CU).
// Staging: global_load_lds (async, ZERO VGPRs per load) into fp32
// double-buffered LDS; counted s_waitcnt vmcnt(8) keeps the next chunk's
// 8 issues in flight across the compute phase (the round-1 version's
// register prefetch was sunk by the compiler -> ~2 loads in flight ->
// 25 us/block latency serialization; VGPR_Count=92 was the tell).
// fp32->bf16 conversion happens at the LDS->frag read.
// Norms: A-row sumsq owned by wn==0 waves (wm selects row-half), B-row
// sumsq owned by wm==0 waves (wn selects row-half); tile ownership
// (doQ/doK) makes every (part,b,row) written exactly once, race-free.
// ---------------------------------------------------------------------------
__global__ __launch_bounds__(256, 2) void gemm1_kernel(const float* __restrict__ q,
                                                       const float* __restrict__ k,
                                                       float* __restrict__ Sp,
                                                       float* __restrict__ nq2p,
                                                       float* __restrict__ nk2p) {
    // two buffers; each: A[128][32] f32 (4096) then B[128][32] f32 (4096)
    __shared__ alignas(16) float lds[16384];   // 64 KB

    const int tid = threadIdx.x;
    const int lane = tid & 63;
    const int wave = tid >> 6;
    const int l15 = lane & 15;
    const int quad = lane >> 4;

    const int bx = blockIdx.x;
    const int tile = bx % 3;               // 0:(0,0) 1:(1,0) 2:(1,1)
    const int part = (bx / 3) % NPARTS;
    const int b = bx / (3 * NPARTS);
    const int tm = (tile + 1) >> 1;
    const int tn = tile >> 1;

    const int wm = wave >> 1;              // m 64-half
    const int wn = wave & 1;               // n 64-half

    const bool doQ = (tile != 2);
    const bool doK = (tile != 1);

    // staging geometry: issue j (0..15) covers rows 8j..8j+7 (1 KB linear);
    // wave w owns issues w*4..w*4+3; lane -> row_local = lane>>3, granule = lane&7
    const int g8 = lane & 7;
    const int rl = lane >> 3;

    const float* qp[4];
    const float* kp[4];
#pragma unroll
    for (int i = 0; i < 4; i++) {
        const int row = wave * 32 + i * 8 + rl;      // 0..127
        const int ta = tm * 128 + row;
        const int rb = tn * 128 + row;
        qp[i] = q + (size_t)b * SB + (size_t)(ta >> 4) * SC + (size_t)(ta & 15) * 128 + g8 * 4;
        kp[i] = k + (size_t)b * SB + (size_t)(rb >> 4) * SC + (size_t)(rb & 15) * 128 + g8 * 4;
    }

    f32x4 acc[4][4] = {};
    bool live[4][4];
#pragma unroll
    for (int mi = 0; mi < 4; mi++)
#pragma unroll
        for (int ni = 0; ni < 4; ni++)
            live[mi][ni] = (tn * 128 + wn * 64 + ni * 16) <= (tm * 128 + wm * 64 + mi * 16);

    float sqA[4] = {0.f, 0.f, 0.f, 0.f};
    float sqB[4] = {0.f, 0.f, 0.f, 0.f};

    // ---- async stage of one 128x32 A-tile + B-tile into buffer p
    auto stage = [&](int ch, int p) {
        const int kg = part * PARTLEN + ch * BK;
        const size_t koff = (size_t)(kg >> 7) * SN + (kg & 127);
#pragma unroll
        for (int i = 0; i < 4; i++)
            __builtin_amdgcn_global_load_lds(
                (const __attribute__((address_space(1))) void*)(qp[i] + koff),
                (__attribute__((address_space(3))) void*)(&lds[p * 8192 + (wave * 4 + i) * 256]),
                16, 0, 0);
#pragma unroll
        for (int i = 0; i < 4; i++)
            __builtin_amdgcn_global_load_lds(
                (const __attribute__((address_space(1))) void*)(kp[i] + koff),
                (__attribute__((address_space(3))) void*)(&lds[p * 8192 + 4096 + (wave * 4 + i) * 256]),
                16, 0, 0);
    };

    stage(0, 0);    // prologue: 8 gll outstanding

    for (int ch = 0; ch < NCH; ch++) {
        const int p = ch & 1;
        if (ch + 1 < NCH) {
            stage(ch + 1, 1 - p);                               // +8 in flight
            asm volatile("s_waitcnt vmcnt(8)" ::: "memory");    // old 8 (buf p) done
        } else {
            asm volatile("s_waitcnt vmcnt(0)" ::: "memory");
        }
        __builtin_amdgcn_s_barrier();            // all waves: buf p fully staged
        __builtin_amdgcn_sched_barrier(0);       // no ds_read hoists above this

        const float* A = &lds[p * 8192];
        const float* B = &lds[p * 8192 + 4096];
        bf16x8 af[4], bfr[4];
#pragma unroll
        for (int mi = 0; mi < 4; mi++) {
            const float4 lo = *(const float4*)&A[(wm * 64 + mi * 16 + l15) * 32 + quad * 8];
            const float4 hi = *(const float4*)&A[(wm * 64 + mi * 16 + l15) * 32 + quad * 8 + 4];
            af[mi] = cvt8(lo, hi);
            if (wn == 0) sqA[mi] += dot4(lo) + dot4(hi);
        }
#pragma unroll
        for (int ni = 0; ni < 4; ni++) {
            const float4 lo = *(const float4*)&B[(wn * 64 + ni * 16 + l15) * 32 + quad * 8];
            const float4 hi = *(const float4*)&B[(wn * 64 + ni * 16 + l15) * 32 + quad * 8 + 4];
            bfr[ni] = cvt8(lo, hi);
            if (wm == 0) sqB[ni] += dot4(lo) + dot4(hi);
        }
#pragma unroll
        for (int mi = 0; mi < 4; mi++)
#pragma unroll
            for (int ni = 0; ni < 4; ni++)
                if (live[mi][ni])
                    acc[mi][ni] = __builtin_amdgcn_mfma_f32_16x16x32_bf16(
                        af[mi], bfr[ni], acc[mi][ni], 0, 0, 0);

        __builtin_amdgcn_sched_barrier(0);       // reads stay above the barrier
        __builtin_amdgcn_s_barrier();            // buf p free for re-staging
        __builtin_amdgcn_sched_barrier(0);       // next stage stays below it
    }

    // ---- Spart epilogue
    float* o = Sp + (size_t)part * SPART + (size_t)b * 65536;
#pragma unroll
    for (int mi = 0; mi < 4; mi++)
#pragma unroll
        for (int ni = 0; ni < 4; ni++) {
            if (!live[mi][ni]) continue;
            const int r = tn * 128 + wn * 64 + ni * 16 + l15;
#pragma unroll
            for (int j = 0; j < 4; j++) {
                const int t = tm * 128 + wm * 64 + mi * 16 + quad * 4 + j;
                o[(size_t)t * 256 + r] = acc[mi][ni][j];
            }
        }

    // ---- sumsq epilogue: reduce across the 4 quads (rows live in l15)
    if (wn == 0 && doQ) {
#pragma unroll
        for (int mi = 0; mi < 4; mi++) {
            float s = sqA[mi];
            s += __shfl_xor(s, 16, 64);
            s += __shfl_xor(s, 32, 64);
            if (lane < 16)
                nq2p[part * 4096 + b * 256 + tm * 128 + wm * 64 + mi * 16 + lane] = s;
        }
    }
    if (wm == 0 && doK) {
#pragma unroll
        for (int ni = 0; ni < 4; ni++) {
            float s = sqB[ni];
            s += __shfl_xor(s, 16, 64);
            s += __shfl_xor(s, 32, 64);
            if (lane < 16)
                nk2p[part * 4096 + b * 256 + tn * 128 + wn * 64 + ni * 16 + lane] = s;
        }
    }
}

// ---------------------------------------------------------------------------
// Kernel 2: sum split-K partials, finalize inverse norms from sumsq partials,
// causal mask, softmax, write P as bf16. One wave per (b,t) row.
// ---------------------------------------------------------------------------
__global__ __launch_bounds__(256) void softmax_kernel(const float* __restrict__ Sp,
                                                      const float* __restrict__ nq2p,
                                                      const float* __restrict__ nk2p,
                                                      __bf16* __restrict__ P) {
    const int wave = threadIdx.x >> 6;
    const int lane = threadIdx.x & 63;
    const int t = blockIdx.x * 4 + wave;
    const int b = blockIdx.y;
    const size_t rowbase = ((size_t)b * 256 + t) * 256;
    const int r0 = lane * 4;

    float4 s4 = {0.f, 0.f, 0.f, 0.f};
#pragma unroll
    for (int p = 0; p < NPARTS; p++) {
        const float4 x = *(const float4*)(Sp + (size_t)p * SPART + rowbase + r0);
        s4.x += x.x; s4.y += x.y; s4.z += x.z; s4.w += x.w;
    }
    float sq = 0.f;
#pragma unroll
    for (int p = 0; p < NPARTS; p++) sq += nq2p[p * 4096 + b * 256 + t];
    float4 sk = {0.f, 0.f, 0.f, 0.f};
#pragma unroll
    for (int p = 0; p < NPARTS; p++) {
        const float4 x = *(const float4*)(nk2p + p * 4096 + b * 256 + r0);
        sk.x += x.x; sk.y += x.y; sk.z += x.z; sk.w += x.w;
    }
    const float qn = 1.0f / fmaxf(sqrtf(sq), 1e-12f);
    float4 kn;
    kn.x = 1.0f / fmaxf(sqrtf(sk.x), 1e-12f);
    kn.y = 1.0f / fmaxf(sqrtf(sk.y), 1e-12f);
    kn.z = 1.0f / fmaxf(sqrtf(sk.z), 1e-12f);
    kn.w = 1.0f / fmaxf(sqrtf(sk.w), 1e-12f);

    float val[4] = {s4.x * qn * kn.x, s4.y * qn * kn.y,
                    s4.z * qn * kn.z, s4.w * qn * kn.w};
    float m = -1e30f;
#pragma unroll
    for (int j = 0; j < 4; j++) {
        if (r0 + j > t) val[j] = -1e30f;
        m = fmaxf(m, val[j]);
    }
#pragma unroll
    for (int off = 32; off; off >>= 1) m = fmaxf(m, __shfl_xor(m, off, 64));

    float e[4], sum = 0.f;
#pragma unroll
    for (int j = 0; j < 4; j++) {
        e[j] = (r0 + j <= t) ? expf(val[j] - m) : 0.f;
        sum += e[j];
    }
#pragma unroll
    for (int off = 32; off; off >>= 1) sum += __shfl_xor(sum, off, 64);

    const float inv = 1.0f / sum;
    bf16x4 o;
    o[0] = (__bf16)(e[0] * inv);
    o[1] = (__bf16)(e[1] * inv);
    o[2] = (__bf16)(e[2] * inv);
    o[3] = (__bf16)(e[3] * inv);
    *(bf16x4*)(P + rowbase + r0) = o;
}

// ---------------------------------------------------------------------------
// Kernel 3: O[t][s] = sum_r P[t][r]*V[r][s] + V[t][s], bf16 MFMA.
// Block = 128 t x 64 s (half of one n), K = 256 r in 4 chunks of 64.
// P A-fragments load DIRECTLY from global (natural [t][r] layout == A-frag
// layout; P is 2 MB, L2-hot). Only V goes through LDS (transposed, paired-row
// b32 stores, XOR swizzle). grid (50 nw, 2 t-tiles, 16 b) = 1600 blocks.
// ---------------------------------------------------------------------------
__global__ __launch_bounds__(256, 4) void gemm2_kernel(const __bf16* __restrict__ P,
                                                       const float* __restrict__ v,
                                                       float* __restrict__ out) {
    __shared__ alignas(16) char smem[9216];
    __bf16* Vs = (__bf16*)smem;     // [64 s][72 r-stride]  (9216 B)
    float* Es = (float*)smem;       // [32][68] epilogue reuse (8704 B)

    const int tid = threadIdx.x;
    const int b = blockIdx.z;
    const int tt = blockIdx.y;      // 0..1 (t 128-half)
    const int nw = blockIdx.x;      // 0..49
    const int n = nw >> 1;
    const int whalf = nw & 1;

    const int lane = tid & 63;
    const int wave = tid >> 6;
    const int wm = wave >> 1;       // t 64-half within 128-tile
    const int wn = wave & 1;        // s 32-half within 64-tile
    const int l15 = lane & 15;
    const int quad = lane >> 4;

    // V staging coords: thread covers s-group vu*8..+7, row pair 2rp, 2rp+1
    const int vu = tid & 7;
    const int rp = tid >> 3;        // 0..31
    const float* vbase = v + (size_t)b * SB + (size_t)n * SN + whalf * 64;

    // P A-frag base: row = tt*128 + wm*64 + mi*16 + l15, col = kc*64+ks*32+quad*8
    const __bf16* Pbase = P + ((size_t)b * 256 + tt * 128 + wm * 64 + l15) * 256 + quad * 8;

    f32x4 acc[4][2] = {};

    for (int kc = 0; kc < 4; kc++) {
        // A fragments direct from global (issued early, L2-hot)
        bf16x8 af[4][2];
#pragma unroll
        for (int mi = 0; mi < 4; mi++)
#pragma unroll
            for (int ks = 0; ks < 2; ks++)
                af[mi][ks] = *(const bf16x8*)(Pbase + (size_t)mi * 16 * 256 + kc * 64 + ks * 32);

        // V loads: rows 2rp, 2rp+1 of this r-chunk, 8 floats each
        float vr0[8], vr1[8];
        {
            const int r0 = kc * 64 + 2 * rp;
            const int r1 = r0 + 1;
            const float* row0 = vbase + (size_t)(r0 >> 4) * SC + (size_t)(r0 & 15) * 128;
            const float* row1 = vbase + (size_t)(r1 >> 4) * SC + (size_t)(r1 & 15) * 128;
            *(float4*)&vr0[0] = *(const float4*)(row0 + vu * 8);
            *(float4*)&vr0[4] = *(const float4*)(row0 + vu * 8 + 4);
            *(float4*)&vr1[0] = *(const float4*)(row1 + vu * 8);
            *(float4*)&vr1[4] = *(const float4*)(row1 + vu * 8 + 4);
        }
        __syncthreads();   // prior Vs reads (or Es init) done
        {
            const int rl0 = 2 * rp;
#pragma unroll
            for (int sj = 0; sj < 8; sj++) {
                const int s = vu * 8 + sj;
                bf16x2 pr;
                pr[0] = (__bf16)vr0[sj];
                pr[1] = (__bf16)vr1[sj];
                *(bf16x2*)&Vs[s * 72 + (rl0 ^ (s & 0x38))] = pr;
            }
        }
        __syncthreads();
#pragma unroll
        for (int ks = 0; ks < 2; ks++) {
            bf16x8 bfr[2];
#pragma unroll
            for (int ni = 0; ni < 2; ni++) {
                const int s = wn * 32 + ni * 16 + l15;
                bfr[ni] = *(const bf16x8*)&Vs[s * 72 + ((ks * 32 + quad * 8) ^ (s & 0x38))];
            }
#pragma unroll
            for (int mi = 0; mi < 4; mi++)
#pragma unroll
                for (int ni = 0; ni < 2; ni++)
                    acc[mi][ni] = __builtin_amdgcn_mfma_f32_16x16x32_bf16(
                        af[mi][ks], bfr[ni], acc[mi][ni], 0, 0, 0);
        }
    }

    // ---- epilogue: 4 passes of 32 t-rows through Es[32][68], coalesced out
    for (int p = 0; p < 4; p++) {
        __syncthreads();   // prior Vs/Es reads done
        if (wm == (p >> 1)) {
            const int mibase = (p & 1) * 2;
#pragma unroll
            for (int mm = 0; mm < 2; mm++)
#pragma unroll
                for (int ni = 0; ni < 2; ni++) {
                    const f32x4 a = acc[mibase + mm][ni];
                    const int wcol = wn * 32 + ni * 16 + l15;
#pragma unroll
                    for (int j = 0; j < 4; j++)
                        Es[(mm * 16 + quad * 4 + j) * 68 + wcol] = a[j];
                }
        }
        __syncthreads();
#pragma unroll
        for (int it = 0; it < 2; it++) {
            const int tl = it * 16 + (tid >> 4);      // 0..31
            const int w4 = (tid & 15) * 4;            // 0..60
            const int t = tt * 128 + p * 32 + tl;
            const size_t a = (size_t)b * SB + (size_t)(t >> 4) * SC + (size_t)n * SN +
                             (size_t)(t & 15) * 128 + whalf * 64 + w4;
            float4 r4 = *(const float4*)&Es[tl * 68 + w4];
            const float4 buf = *(const float4*)(v + a);
            r4.x += buf.x; r4.y += buf.y; r4.z += buf.z; r4.w += buf.w;
            *(float4*)(out + a) = r4;
        }
    }
}

// ---------------------------------------------------------------------------
extern "C" void kernel_launch(void* const* d_in, const int* in_sizes, int n_in,
                              void* d_out, int out_size, void* d_ws, size_t ws_size,
                              hipStream_t stream) {
    const float* q = (const float*)d_in[0];
    const float* k = (const float*)d_in[1];
    const float* v = (const float*)d_in[2];
    float* out = (float*)d_out;

    float* ws = (float*)d_ws;
    float* nq2p = ws;                          // 10*4096 floats (sumsq partials)
    float* nk2p = ws + 40960;                  // 10*4096 floats
    __bf16* P = (__bf16*)(ws + 81920);         // 16*256*256 bf16 = 2 MB

    // d_out doubles as split-K scratch (10 * 4 MB = 42 MB <= 52 MB out),
    // fully overwritten by gemm2 afterwards.
    float* Spart = out;

    gemm1_kernel<<<dim3(G1BLOCKS), dim3(256), 0, stream>>>(q, k, Spart, nq2p, nk2p);
    softmax_kernel<<<dim3(64, 16), dim3(256), 0, stream>>>(Spart, nq2p, nk2p, P);
    gemm2_kernel<<<dim3(50, 2, 16), dim3(256), 0, stream>>>(P, v, out);
}

// Round 3
// 217.356 us; speedup vs baseline: 1.0683x; 1.0683x over previous
//
#include <hip/hip_runtime.h>
#include <math.h>

// Problem constants: token shape (b=16, c=16, n=25, h=16, w=128)
#define SB 819200   // batch stride = c*n*h*w
#define SC 51200    // c stride    = n*h*w
#define SN 2048     // n stride    = h*w
#define CH 256      // c*h  (t dim)
#define NW 3200     // n*w  (k dim of gemm1, s dim of gemm2)
#define NPARTS 10
#define PARTLEN 320         // 3200 / 10
#define BK 32               // k-chunk per stage
#define NCH 10              // PARTLEN / BK
#define SPART 1048576       // 16*256*256 floats per split-K partial
#define G1BLOCKS 480        // 3 tiles * 10 parts * 16 b

typedef __bf16 bf16x8 __attribute__((ext_vector_type(8)));
typedef __bf16 bf16x4 __attribute__((ext_vector_type(4)));
typedef __bf16 bf16x2 __attribute__((ext_vector_type(2)));
typedef float  f32x4  __attribute__((ext_vector_type(4)));

__device__ __forceinline__ bf16x8 cvt8(float4 a, float4 b) {
    bf16x8 r;
    r[0] = (__bf16)a.x; r[1] = (__bf16)a.y; r[2] = (__bf16)a.z; r[3] = (__bf16)a.w;
    r[4] = (__bf16)b.x; r[5] = (__bf16)b.y; r[6] = (__bf16)b.z; r[7] = (__bf16)b.w;
    return r;
}

__device__ __forceinline__ float dot4(float4 a) {
    return a.x * a.x + a.y * a.y + a.z * a.z + a.w * a.w;
}

// ---------------------------------------------------------------------------
// Kernel 1: split-K bf16-MFMA score GEMM + fused row sum-of-squares.
// Spart[p][b][t][r] = sum_{k in part p} Q[t][k]*K[r][k], fp32.
// 128x128 tile, 4 waves of 64x64, causal 3-tile, 480 blocks (2/CU).
// Staging: global_load_lds into fp32 double-buffered LDS, counted vmcnt(8).
// BANK-CONFLICT FIX (round 2 was 16-way conflicted, 1.5e7 conflict cycles):
// LDS dest of global_load_lds must stay linear, so the XOR swizzle is done
// on the SOURCE granule: lane (rl,g8) loads source 16B-granule (g8 ^ rl) of
// its row (bijective within the 128B row segment -> coalescing preserved).
// Read side: lo/hi fragment float4s sit at LDS granules (2q)^(row&7) and
// (2q+1)^(row&7) -> for the 16 rows of a fragment each quad sweeps all 8
// granules -> 2 lanes/bank over the wave = conflict-free.
// ---------------------------------------------------------------------------
__global__ __launch_bounds__(256, 2) void gemm1_kernel(const float* __restrict__ q,
                                                       const float* __restrict__ k,
                                                       float* __restrict__ Sp,
                                                       float* __restrict__ nq2p,
                                                       float* __restrict__ nk2p) {
    // two buffers; each: A[128][32] f32 (4096) then B[128][32] f32 (4096)
    __shared__ alignas(16) float lds[16384];   // 64 KB

    const int tid = threadIdx.x;
    const int lane = tid & 63;
    const int wave = tid >> 6;
    const int l15 = lane & 15;
    const int quad = lane >> 4;

    const int bx = blockIdx.x;
    const int tile = bx % 3;               // 0:(0,0) 1:(1,0) 2:(1,1)
    const int part = (bx / 3) % NPARTS;
    const int b = bx / (3 * NPARTS);
    const int tm = (tile + 1) >> 1;
    const int tn = tile >> 1;

    const int wm = wave >> 1;              // m 64-half
    const int wn = wave & 1;               // n 64-half

    const bool doQ = (tile != 2);
    const bool doK = (tile != 1);

    // staging geometry: issue j (0..15) covers rows 8j..8j+7 (1 KB linear);
    // wave w owns issues w*4..w*4+3; lane -> row_local = lane>>3, granule = lane&7
    const int g8 = lane & 7;
    const int rl = lane >> 3;
    const int gsrc = g8 ^ rl;              // swizzled source granule

    const float* qp[4];
    const float* kp[4];
#pragma unroll
    for (int i = 0; i < 4; i++) {
        const int row = wave * 32 + i * 8 + rl;      // 0..127
        const int ta = tm * 128 + row;
        const int rb = tn * 128 + row;
        qp[i] = q + (size_t)b * SB + (size_t)(ta >> 4) * SC + (size_t)(ta & 15) * 128 + gsrc * 4;
        kp[i] = k + (size_t)b * SB + (size_t)(rb >> 4) * SC + (size_t)(rb & 15) * 128 + gsrc * 4;
    }

    // fragment-read word offsets within a row (swizzle-matched, per-lane const)
    const int e3 = l15 & 7;
    const int gl = ((2 * quad) ^ e3) * 4;      // lo granule word offset
    const int gh = ((2 * quad + 1) ^ e3) * 4;  // hi granule word offset

    f32x4 acc[4][4] = {};
    bool live[4][4];
#pragma unroll
    for (int mi = 0; mi < 4; mi++)
#pragma unroll
        for (int ni = 0; ni < 4; ni++)
            live[mi][ni] = (tn * 128 + wn * 64 + ni * 16) <= (tm * 128 + wm * 64 + mi * 16);

    float sqA[4] = {0.f, 0.f, 0.f, 0.f};
    float sqB[4] = {0.f, 0.f, 0.f, 0.f};

    // ---- async stage of one 128x32 A-tile + B-tile into buffer p
    auto stage = [&](int ch, int p) {
        const int kg = part * PARTLEN + ch * BK;
        const size_t koff = (size_t)(kg >> 7) * SN + (kg & 127);
#pragma unroll
        for (int i = 0; i < 4; i++)
            __builtin_amdgcn_global_load_lds(
                (const __attribute__((address_space(1))) void*)(qp[i] + koff),
                (__attribute__((address_space(3))) void*)(&lds[p * 8192 + (wave * 4 + i) * 256]),
                16, 0, 0);
#pragma unroll
        for (int i = 0; i < 4; i++)
            __builtin_amdgcn_global_load_lds(
                (const __attribute__((address_space(1))) void*)(kp[i] + koff),
                (__attribute__((address_space(3))) void*)(&lds[p * 8192 + 4096 + (wave * 4 + i) * 256]),
                16, 0, 0);
    };

    stage(0, 0);    // prologue: 8 gll outstanding

    for (int ch = 0; ch < NCH; ch++) {
        const int p = ch & 1;
        if (ch + 1 < NCH) {
            stage(ch + 1, 1 - p);                               // +8 in flight
            asm volatile("s_waitcnt vmcnt(8)" ::: "memory");    // old 8 (buf p) done
        } else {
            asm volatile("s_waitcnt vmcnt(0)" ::: "memory");
        }
        __builtin_amdgcn_s_barrier();            // all waves: buf p fully staged
        __builtin_amdgcn_sched_barrier(0);       // no ds_read hoists above this

        const float* A = &lds[p * 8192];
        const float* B = &lds[p * 8192 + 4096];
        bf16x8 af[4], bfr[4];
#pragma unroll
        for (int mi = 0; mi < 4; mi++) {
            const int rw = (wm * 64 + mi * 16 + l15) * 32;
            const float4 lo = *(const float4*)&A[rw + gl];
            const float4 hi = *(const float4*)&A[rw + gh];
            af[mi] = cvt8(lo, hi);
            if (wn == 0) sqA[mi] += dot4(lo) + dot4(hi);
        }
#pragma unroll
        for (int ni = 0; ni < 4; ni++) {
            const int rw = (wn * 64 + ni * 16 + l15) * 32;
            const float4 lo = *(const float4*)&B[rw + gl];
            const float4 hi = *(const float4*)&B[rw + gh];
            bfr[ni] = cvt8(lo, hi);
            if (wm == 0) sqB[ni] += dot4(lo) + dot4(hi);
        }
#pragma unroll
        for (int mi = 0; mi < 4; mi++)
#pragma unroll
            for (int ni = 0; ni < 4; ni++)
                if (live[mi][ni])
                    acc[mi][ni] = __builtin_amdgcn_mfma_f32_16x16x32_bf16(
                        af[mi], bfr[ni], acc[mi][ni], 0, 0, 0);

        __builtin_amdgcn_sched_barrier(0);       // reads stay above the barrier
        __builtin_amdgcn_s_barrier();            // buf p free for re-staging
        __builtin_amdgcn_sched_barrier(0);       // next stage stays below it
    }

    // ---- Spart epilogue
    float* o = Sp + (size_t)part * SPART + (size_t)b * 65536;
#pragma unroll
    for (int mi = 0; mi < 4; mi++)
#pragma unroll
        for (int ni = 0; ni < 4; ni++) {
            if (!live[mi][ni]) continue;
            const int r = tn * 128 + wn * 64 + ni * 16 + l15;
#pragma unroll
            for (int j = 0; j < 4; j++) {
                const int t = tm * 128 + wm * 64 + mi * 16 + quad * 4 + j;
                o[(size_t)t * 256 + r] = acc[mi][ni][j];
            }
        }

    // ---- sumsq epilogue: reduce across the 4 quads (rows live in l15)
    if (wn == 0 && doQ) {
#pragma unroll
        for (int mi = 0; mi < 4; mi++) {
            float s = sqA[mi];
            s += __shfl_xor(s, 16, 64);
            s += __shfl_xor(s, 32, 64);
            if (lane < 16)
                nq2p[part * 4096 + b * 256 + tm * 128 + wm * 64 + mi * 16 + lane] = s;
        }
    }
    if (wm == 0 && doK) {
#pragma unroll
        for (int ni = 0; ni < 4; ni++) {
            float s = sqB[ni];
            s += __shfl_xor(s, 16, 64);
            s += __shfl_xor(s, 32, 64);
            if (lane < 16)
                nk2p[part * 4096 + b * 256 + tn * 128 + wn * 64 + ni * 16 + lane] = s;
        }
    }
}

// ---------------------------------------------------------------------------
// Kernel 2: sum split-K partials, finalize inverse norms from sumsq partials,
// causal mask, softmax, write P as bf16. One wave per (b,t) row.
// ---------------------------------------------------------------------------
__global__ __launch_bounds__(256) void softmax_kernel(const float* __restrict__ Sp,
                                                      const float* __restrict__ nq2p,
                                                      const float* __restrict__ nk2p,
                                                      __bf16* __restrict__ P) {
    const int wave = threadIdx.x >> 6;
    const int lane = threadIdx.x & 63;
    const int t = blockIdx.x * 4 + wave;
    const int b = blockIdx.y;
    const size_t rowbase = ((size_t)b * 256 + t) * 256;
    const int r0 = lane * 4;

    float4 s4 = {0.f, 0.f, 0.f, 0.f};
#pragma unroll
    for (int p = 0; p < NPARTS; p++) {
        const float4 x = *(const float4*)(Sp + (size_t)p * SPART + rowbase + r0);
        s4.x += x.x; s4.y += x.y; s4.z += x.z; s4.w += x.w;
    }
    float sq = 0.f;
#pragma unroll
    for (int p = 0; p < NPARTS; p++) sq += nq2p[p * 4096 + b * 256 + t];
    float4 sk = {0.f, 0.f, 0.f, 0.f};
#pragma unroll
    for (int p = 0; p < NPARTS; p++) {
        const float4 x = *(const float4*)(nk2p + p * 4096 + b * 256 + r0);
        sk.x += x.x; sk.y += x.y; sk.z += x.z; sk.w += x.w;
    }
    const float qn = 1.0f / fmaxf(sqrtf(sq), 1e-12f);
    float4 kn;
    kn.x = 1.0f / fmaxf(sqrtf(sk.x), 1e-12f);
    kn.y = 1.0f / fmaxf(sqrtf(sk.y), 1e-12f);
    kn.z = 1.0f / fmaxf(sqrtf(sk.z), 1e-12f);
    kn.w = 1.0f / fmaxf(sqrtf(sk.w), 1e-12f);

    float val[4] = {s4.x * qn * kn.x, s4.y * qn * kn.y,
                    s4.z * qn * kn.z, s4.w * qn * kn.w};
    float m = -1e30f;
#pragma unroll
    for (int j = 0; j < 4; j++) {
        if (r0 + j > t) val[j] = -1e30f;
        m = fmaxf(m, val[j]);
    }
#pragma unroll
    for (int off = 32; off; off >>= 1) m = fmaxf(m, __shfl_xor(m, off, 64));

    float e[4], sum = 0.f;
#pragma unroll
    for (int j = 0; j < 4; j++) {
        e[j] = (r0 + j <= t) ? expf(val[j] - m) : 0.f;
        sum += e[j];
    }
#pragma unroll
    for (int off = 32; off; off >>= 1) sum += __shfl_xor(sum, off, 64);

    const float inv = 1.0f / sum;
    bf16x4 o;
    o[0] = (__bf16)(e[0] * inv);
    o[1] = (__bf16)(e[1] * inv);
    o[2] = (__bf16)(e[2] * inv);
    o[3] = (__bf16)(e[3] * inv);
    *(bf16x4*)(P + rowbase + r0) = o;
}

// ---------------------------------------------------------------------------
// Kernel 3: O[t][s] = sum_r P[t][r]*V[r][s] + V[t][s], bf16 MFMA.
// Block = 128 t x 64 s (half of one n), K = 256 r in 4 chunks of 64.
// P A-fragments load DIRECTLY from global (natural [t][r] layout == A-frag
// layout; P is 2 MB, L2-hot). Only V goes through LDS (transposed, paired-row
// b32 stores, XOR swizzle). grid (50 nw, 2 t-tiles, 16 b) = 1600 blocks.
// ---------------------------------------------------------------------------
__global__ __launch_bounds__(256, 4) void gemm2_kernel(const __bf16* __restrict__ P,
                                                       const float* __restrict__ v,
                                                       float* __restrict__ out) {
    __shared__ alignas(16) char smem[9216];
    __bf16* Vs = (__bf16*)smem;     // [64 s][72 r-stride]  (9216 B)
    float* Es = (float*)smem;       // [32][68] epilogue reuse (8704 B)

    const int tid = threadIdx.x;
    const int b = blockIdx.z;
    const int tt = blockIdx.y;      // 0..1 (t 128-half)
    const int nw = blockIdx.x;      // 0..49
    const int n = nw >> 1;
    const int whalf = nw & 1;

    const int lane = tid & 63;
    const int wave = tid >> 6;
    const int wm = wave >> 1;       // t 64-half within 128-tile
    const int wn = wave & 1;        // s 32-half within 64-tile
    const int l15 = lane & 15;
    const int quad = lane >> 4;

    // V staging coords: thread covers s-group vu*8..+7, row pair 2rp, 2rp+1
    const int vu = tid & 7;
    const int rp = tid >> 3;        // 0..31
    const float* vbase = v + (size_t)b * SB + (size_t)n * SN + whalf * 64;

    // P A-frag base: row = tt*128 + wm*64 + mi*16 + l15, col = kc*64+ks*32+quad*8
    const __bf16* Pbase = P + ((size_t)b * 256 + tt * 128 + wm * 64 + l15) * 256 + quad * 8;

    f32x4 acc[4][2] = {};

    for (int kc = 0; kc < 4; kc++) {
        // A fragments direct from global (issued early, L2-hot)
        bf16x8 af[4][2];
#pragma unroll
        for (int mi = 0; mi < 4; mi++)
#pragma unroll
            for (int ks = 0; ks < 2; ks++)
                af[mi][ks] = *(const bf16x8*)(Pbase + (size_t)mi * 16 * 256 + kc * 64 + ks * 32);

        // V loads: rows 2rp, 2rp+1 of this r-chunk, 8 floats each
        float vr0[8], vr1[8];
        {
            const int r0 = kc * 64 + 2 * rp;
            const int r1 = r0 + 1;
            const float* row0 = vbase + (size_t)(r0 >> 4) * SC + (size_t)(r0 & 15) * 128;
            const float* row1 = vbase + (size_t)(r1 >> 4) * SC + (size_t)(r1 & 15) * 128;
            *(float4*)&vr0[0] = *(const float4*)(row0 + vu * 8);
            *(float4*)&vr0[4] = *(const float4*)(row0 + vu * 8 + 4);
            *(float4*)&vr1[0] = *(const float4*)(row1 + vu * 8);
            *(float4*)&vr1[4] = *(const float4*)(row1 + vu * 8 + 4);
        }
        __syncthreads();   // prior Vs reads (or Es init) done
        {
            const int rl0 = 2 * rp;
#pragma unroll
            for (int sj = 0; sj < 8; sj++) {
                const int s = vu * 8 + sj;
                bf16x2 pr;
                pr[0] = (__bf16)vr0[sj];
                pr[1] = (__bf16)vr1[sj];
                *(bf16x2*)&Vs[s * 72 + (rl0 ^ (s & 0x38))] = pr;
            }
        }
        __syncthreads();
#pragma unroll
        for (int ks = 0; ks < 2; ks++) {
            bf16x8 bfr[2];
#pragma unroll
            for (int ni = 0; ni < 2; ni++) {
                const int s = wn * 32 + ni * 16 + l15;
                bfr[ni] = *(const bf16x8*)&Vs[s * 72 + ((ks * 32 + quad * 8) ^ (s & 0x38))];
            }
#pragma unroll
            for (int mi = 0; mi < 4; mi++)
#pragma unroll
                for (int ni = 0; ni < 2; ni++)
                    acc[mi][ni] = __builtin_amdgcn_mfma_f32_16x16x32_bf16(
                        af[mi][ks], bfr[ni], acc[mi][ni], 0, 0, 0);
        }
    }

    // ---- epilogue: 4 passes of 32 t-rows through Es[32][68], coalesced out
    for (int p = 0; p < 4; p++) {
        __syncthreads();   // prior Vs/Es reads done
        if (wm == (p >> 1)) {
            const int mibase = (p & 1) * 2;
#pragma unroll
            for (int mm = 0; mm < 2; mm++)
#pragma unroll
                for (int ni = 0; ni < 2; ni++) {
                    const f32x4 a = acc[mibase + mm][ni];
                    const int wcol = wn * 32 + ni * 16 + l15;
#pragma unroll
                    for (int j = 0; j < 4; j++)
                        Es[(mm * 16 + quad * 4 + j) * 68 + wcol] = a[j];
                }
        }
        __syncthreads();
#pragma unroll
        for (int it = 0; it < 2; it++) {
            const int tl = it * 16 + (tid >> 4);      // 0..31
            const int w4 = (tid & 15) * 4;            // 0..60
            const int t = tt * 128 + p * 32 + tl;
            const size_t a = (size_t)b * SB + (size_t)(t >> 4) * SC + (size_t)n * SN +
                             (size_t)(t & 15) * 128 + whalf * 64 + w4;
            float4 r4 = *(const float4*)&Es[tl * 68 + w4];
            const float4 buf = *(const float4*)(v + a);
            r4.x += buf.x; r4.y += buf.y; r4.z += buf.z; r4.w += buf.w;
            *(float4*)(out + a) = r4;
        }
    }
}

// ---------------------------------------------------------------------------
extern "C" void kernel_launch(void* const* d_in, const int* in_sizes, int n_in,
                              void* d_out, int out_size, void* d_ws, size_t ws_size,
                              hipStream_t stream) {
    const float* q = (const float*)d_in[0];
    const float* k = (const float*)d_in[1];
    const float* v = (const float*)d_in[2];
    float* out = (float*)d_out;

    float* ws = (float*)d_ws;
    float* nq2p = ws;                          // 10*4096 floats (sumsq partials)
    float* nk2p = ws + 40960;                  // 10*4096 floats
    __bf16* P = (__bf16*)(ws + 81920);         // 2 MB

    // d_out doubles as split-K scratch (10 * 4 MB = 42 MB <= 52 MB out),
    // fully overwritten by gemm2 afterwards.
    float* Spart = out;

    gemm1_kernel<<<dim3(G1BLOCKS), dim3(256), 0, stream>>>(q, k, Spart, nq2p, nk2p);
    softmax_kernel<<<dim3(64, 16), dim3(256), 0, stream>>>(Spart, nq2p, nk2p, P);
    gemm2_kernel<<<dim3(50, 2, 16), dim3(256), 0, stream>>>(P, v, out);
}